// Round 10
// baseline (155.949 us; speedup 1.0000x reference)
//
#include <hip/hip_runtime.h>
#include <hip/hip_bf16.h>
#include <stdint.h>

// out[b,n,o] = sum_t x[b,n,t] * (sum_g y[b,g]*w[g,o,t]*mask[o,t]) + bias[o]
// B=32 N=256 T=1024 O=1024 G=8.  bf16 MFMA path (absmax 0.031 vs thr 0.154).
//
//  R18: prep = R5 exact (41.6us; 2.8 TB/s wall, 6 theories falsified -> leave).
//       gemm TILE RESHAPE for TLP: R9 analysis -> 27us at 8 waves/CU (17% occ),
//       2 blocks/CU capped by 64KB LDS; per-tile gaps have no wave to fill.
//       Now BM=64 BN=128 BK=64: LDS 48KB -> 3 blocks/CU, 12 waves/CU, grid
//       (32,4,8)=1024 blocks.  Proven 128B-row xor swizzle kept.  Counted
//       vmcnt(6) dbuf kept (R9: neutral but harmless).  Wave tile 32x64,
//       acc[2], stage 2A+4B loads/thread/tile.
//       R9 ledger: counted-vmcnt vs syncthreads ~= neutral at warm L3 (R8's
//       43us gemm was nt-store L3-cooling confound, not pipeline gain).

#define B_ 32
#define N_ 256
#define T_ 1024
#define O_ 1024
#define G_ 8

#define WSTRIDE ((size_t)(O_ * T_ + 2048))   // padded b-slice stride, elems

#define BM 64
#define BN 128
#define BK 64            // elems; LDS row = 128 B = 8 x 16 B chunks
#define LA_BUF (BM * BK) // 4096 elems = 8 KiB
#define LB_BUF (BN * BK) // 8192 elems = 16 KiB
#define NT (T_ / BK)     // 16 k-tiles

typedef __attribute__((__ext_vector_type__(8)))  __bf16 bf16x8;
typedef __attribute__((__ext_vector_type__(16))) float  f32x16;

__device__ __forceinline__ unsigned short f2bf(float f) {
    union { float f; uint32_t u; } v; v.f = f;
    uint32_t u = v.u;
    uint32_t r = (u + 0x7fffu + ((u >> 16) & 1u)) >> 16;  // RNE
    return (unsigned short)r;
}

__device__ __forceinline__ uint4 pack8(const float* a) {
    uint4 r;
    r.x = (uint32_t)f2bf(a[0]) | ((uint32_t)f2bf(a[1]) << 16);
    r.y = (uint32_t)f2bf(a[2]) | ((uint32_t)f2bf(a[3]) << 16);
    r.z = (uint32_t)f2bf(a[4]) | ((uint32_t)f2bf(a[5]) << 16);
    r.w = (uint32_t)f2bf(a[6]) | ((uint32_t)f2bf(a[7]) << 16);
    return r;
}

#define MIXB 1024   // O*T/4 threads / 256
#define CVTB 1024   // 262144 threads, 8 float4 each

// --- K1: fused prologue (R5 exact).
__global__ __launch_bounds__(256) void prep_kernel(
    const float* __restrict__ w,     // [G,O,T]
    const float* __restrict__ mask,  // [O,T]
    const float* __restrict__ y,     // [B,G]
    const float* __restrict__ x,     // [B,N,T]
    unsigned short* __restrict__ Wb, // [B][WSTRIDE] bf16 (padded)
    unsigned short* __restrict__ xb) // [B,N,T] bf16
{
    const int tid = threadIdx.x;
    if (blockIdx.x < MIXB) {
        __shared__ float ys[B_ * G_];          // 1 KiB
        ys[tid] = y[tid];
        __syncthreads();

        const int idx = blockIdx.x * 256 + tid;   // over O*T/4
        const int o   = idx >> 8;
        const int t   = (idx & 255) << 2;

        const float4 m4 = *(const float4*)(mask + (size_t)o * T_ + t);

        float wv[G_][4];
#pragma unroll
        for (int g = 0; g < G_; ++g) {
            const float4 a = *(const float4*)(w + ((size_t)g * O_ + o) * T_ + t);
            wv[g][0] = a.x * m4.x; wv[g][1] = a.y * m4.y;
            wv[g][2] = a.z * m4.z; wv[g][3] = a.w * m4.w;
        }
        unsigned short* dst = Wb + (size_t)o * T_ + t;
        const int bph = blockIdx.x & (B_ - 1);
#pragma unroll 4
        for (int bi = 0; bi < B_; ++bi) {
            const int b = (bi + bph) & (B_ - 1);
            const float4 y0 = *(const float4*)(ys + b * G_);      // LDS broadcast
            const float4 y1 = *(const float4*)(ys + b * G_ + 4);
            const float yv[G_] = {y0.x, y0.y, y0.z, y0.w, y1.x, y1.y, y1.z, y1.w};
            float acc[4] = {};
#pragma unroll
            for (int g = 0; g < G_; ++g)
#pragma unroll
                for (int j = 0; j < 4; ++j)
                    acc[j] += yv[g] * wv[g][j];
            ushort4 pk;
            pk.x = f2bf(acc[0]); pk.y = f2bf(acc[1]);
            pk.z = f2bf(acc[2]); pk.w = f2bf(acc[3]);
            *(ushort4*)(dst + (size_t)b * WSTRIDE) = pk;
        }
    } else {
        const int i = (blockIdx.x - MIXB) * 256 + tid;
        const float4* x4 = (const float4*)x;
        uint4* o4 = (uint4*)xb;
#pragma unroll
        for (int j = 0; j < 4; ++j) {
            const size_t f4 = (size_t)j * 524288 + (size_t)i * 2;
            const float4 a = x4[f4];
            const float4 b = x4[f4 + 1];
            const float v[8] = {a.x, a.y, a.z, a.w, b.x, b.y, b.z, b.w};
            o4[(size_t)j * 262144 + i] = pack8(v);
        }
    }
}

__device__ __forceinline__ void load16_to_lds(const unsigned short* g, unsigned short* l) {
    __builtin_amdgcn_global_load_lds(
        (const __attribute__((address_space(1))) unsigned char*)g,
        (__attribute__((address_space(3))) unsigned char*)l,
        16, 0, 0);
}

#define VMCNT_6 asm volatile("s_waitcnt vmcnt(6)" ::: "memory")
#define VMCNT_0 asm volatile("s_waitcnt vmcnt(0)" ::: "memory")
#define BARRIER asm volatile("s_barrier" ::: "memory")

// --- K2: batched GEMM, C = A . B^T, K-major bf16, mfma_32x32x16.
// 256 threads = 4 waves (2m x 2n), wave tile 32x64: acc[2] (ni=0,1), mi=1.
// A-frag: m=lane&31, k=(lane>>5)*8+j; B-frag symmetric.
// C/D: col=lane&31, row=(reg&3)+8*(reg>>2)+4*(lane>>5) [m74/m101].
// LDS chunk c of row r holds global chunk (c ^ (r&7)) -> conflict-free b128.
// Grid = (b, tm, tn): XCD = linear%8 = b%8 -> same-b blocks colocate on an XCD.
// Counted-vmcnt dbuf: 6 loads/tile/thread; tile t+1's ride across barriers.
__global__ __launch_bounds__(256, 3) void gemm_kernel(
    const unsigned short* __restrict__ xb,   // [B][N_][T_] bf16
    const unsigned short* __restrict__ Wb,   // [B][WSTRIDE] bf16 (padded)
    const float* __restrict__ bias,          // [O_]
    float* __restrict__ out)                 // [B][N_][O_] f32
{
    __shared__ __align__(16) unsigned short lA[2 * LA_BUF];  // 16 KiB
    __shared__ __align__(16) unsigned short lB[2 * LB_BUF];  // 32 KiB

    const int b  = blockIdx.x;   // 0..31  (XCD = b%8)
    const int tm = blockIdx.y;   // 0..3   (n tiles, 64 rows)
    const int tn = blockIdx.z;   // 0..7   (o tiles, 128 cols)

    const int tid  = threadIdx.x;
    const int lane = tid & 63;
    const int wave = tid >> 6;          // 0..3
    const int wm   = (wave >> 1) * 32;  // 0/32
    const int wn   = (wave & 1) * 64;   // 0/64

    const unsigned short* Ab = xb + (size_t)b * N_ * T_ + (size_t)(tm * BM) * T_;
    const unsigned short* Bb = Wb + (size_t)b * WSTRIDE + (size_t)(tn * BN) * T_;

    // staging: round i: LDS elem tid*8 + i*2048 -> row tid/8 + i*32, chunk tid&7
    const int srow   = tid >> 3;                 // 0..31
    const int schunk = (tid & 7) ^ (srow & 7);   // (i*32)&7==0 -> round-invariant
    const unsigned short* ga0 = Ab + (size_t)srow * T_ + schunk * 8;
    const unsigned short* gb0 = Bb + (size_t)srow * T_ + schunk * 8;

#define STAGE(buf, kt)                                                          \
    {                                                                           \
        unsigned short* lad = lA + (buf) * LA_BUF + tid * 8;                    \
        unsigned short* lbd = lB + (buf) * LB_BUF + tid * 8;                    \
        _Pragma("unroll")                                                       \
        for (int i_ = 0; i_ < 2; ++i_)                                          \
            load16_to_lds(ga0 + (kt) + (size_t)(i_ * 32) * T_, lad + i_ * 2048);\
        _Pragma("unroll")                                                       \
        for (int i_ = 0; i_ < 4; ++i_)                                          \
            load16_to_lds(gb0 + (kt) + (size_t)(i_ * 32) * T_, lbd + i_ * 2048);\
    }

    f32x16 acc[2] = {};

    const int fr   = lane & 31;      // fragment row within 32
    const int half = lane >> 5;      // k-half 0/1 (8 elems each)
    const int sw   = fr & 7;         // swizzle term (wm, wn, i*32 multiples of 8... 32%8==0)

#define COMPUTE(buf)                                                            \
    {                                                                           \
        const unsigned short* la = lA + (buf) * LA_BUF;                         \
        const unsigned short* lb = lB + (buf) * LB_BUF;                         \
        _Pragma("unroll")                                                       \
        for (int ks = 0; ks < 4; ++ks) {                                        \
            const int cp = (((ks * 2 + half)) ^ sw) * 8;                        \
            bf16x8 afr, bfr[2];                                                 \
            afr = *(const bf16x8*)(la + (wm + fr) * BK + cp);                   \
            _Pragma("unroll")                                                   \
            for (int i_ = 0; i_ < 2; ++i_)                                      \
                bfr[i_] = *(const bf16x8*)(lb + (wn + i_ * 32 + fr) * BK + cp); \
            _Pragma("unroll")                                                   \
            for (int ni = 0; ni < 2; ++ni)                                      \
                acc[ni] = __builtin_amdgcn_mfma_f32_32x32x16_bf16(              \
                    afr, bfr[ni], acc[ni], 0, 0, 0);                            \
        }                                                                       \
    }

    STAGE(0, 0)
    STAGE(1, BK)
    // steady state: 12 loads in flight (6 per tile).  vmcnt(6) completes tile
    // t (oldest 6); tile t+1's 6 ride across the barriers.
    for (int t = 0; t < NT - 1; ++t) {
        const int c = t & 1;
        VMCNT_6;
        BARRIER;                       // buf c complete on all waves
        COMPUTE(c)
        BARRIER;                       // all waves done reading buf c
        if (t < NT - 2) STAGE(c, (t + 2) * BK)
    }
    VMCNT_0;
    BARRIER;                           // last tile staged everywhere
    COMPUTE(1)

    // Epilogue: D col=lane&31, row=(reg&3)+8*(reg>>2)+4*(lane>>5)  + bias.
    float* outb = out + (size_t)b * N_ * O_ + (size_t)(tm * BM) * O_ + (tn * BN);
    const int cn = lane & 31;
    const int rb = (lane >> 5) * 4;
#pragma unroll
    for (int ni = 0; ni < 2; ++ni) {
        const int col = wn + ni * 32 + cn;
        const float bv = bias[tn * BN + col];
#pragma unroll
        for (int r = 0; r < 16; ++r) {
            const int row = wm + rb + (r & 3) + 8 * (r >> 2);
            outb[(size_t)row * O_ + col] = acc[ni][r] + bv;
        }
    }
}

// --- Fallback (ws too small): correct fp32 path.
__global__ __launch_bounds__(256) void naive_kernel(
    const float* __restrict__ x, const float* __restrict__ y,
    const float* __restrict__ w, const float* __restrict__ mask,
    const float* __restrict__ bias, float* __restrict__ out)
{
    const int oc = blockIdx.x & 3;
    const int n  = (blockIdx.x >> 2) & (N_ - 1);
    const int b  = blockIdx.x >> 10;

    __shared__ float xs[T_];
    __shared__ float ys[G_];
    const float* xrow = x + ((size_t)b * N_ + n) * T_;
    for (int i = threadIdx.x; i < T_ / 4; i += 256)
        ((float4*)xs)[i] = ((const float4*)xrow)[i];
    if (threadIdx.x < G_) ys[threadIdx.x] = y[b * G_ + threadIdx.x];
    __syncthreads();

    const int o = oc * 256 + threadIdx.x;
    float acc = 0.f;
    for (int t = 0; t < T_; t += 4) {
        const float4 m4 = *(const float4*)(mask + (size_t)o * T_ + t);
        float4 s = {0.f, 0.f, 0.f, 0.f};
#pragma unroll
        for (int g = 0; g < G_; ++g) {
            const float4 w4 = *(const float4*)(w + ((size_t)g * O_ + o) * T_ + t);
            const float yv = ys[g];
            s.x += yv * w4.x; s.y += yv * w4.y; s.z += yv * w4.z; s.w += yv * w4.w;
        }
        acc += xs[t] * m4.x * s.x + xs[t + 1] * m4.y * s.y
             + xs[t + 2] * m4.z * s.z + xs[t + 3] * m4.w * s.w;
    }
    out[((size_t)b * N_ + n) * O_ + o] = acc + bias[o];
}

extern "C" void kernel_launch(void* const* d_in, const int* in_sizes, int n_in,
                              void* d_out, int out_size, void* d_ws, size_t ws_size,
                              hipStream_t stream) {
    const float* x    = (const float*)d_in[0];
    const float* y    = (const float*)d_in[1];
    const float* w    = (const float*)d_in[2];
    const float* mask = (const float*)d_in[3];
    const float* bias = (const float*)d_in[4];
    float* out = (float*)d_out;

    const size_t wb_bytes = (size_t)B_ * WSTRIDE * sizeof(unsigned short); // 64 MiB + 128 KB
    const size_t xb_bytes = (size_t)B_ * N_ * T_ * sizeof(unsigned short); // 16 MiB

    if (ws_size >= wb_bytes + xb_bytes) {
        unsigned short* Wb = (unsigned short*)d_ws;
        unsigned short* xb = (unsigned short*)((char*)d_ws + wb_bytes);
        prep_kernel<<<MIXB + CVTB, 256, 0, stream>>>(w, mask, y, x, Wb, xb);
        dim3 grid(B_, N_ / BM, O_ / BN);   // x=b -> XCD=b%8: A,B L2-resident
        gemm_kernel<<<grid, 256, 0, stream>>>(xb, Wb, bias, out);
    } else {
        naive_kernel<<<B_ * N_ * (O_ / 256), 256, 0, stream>>>(x, y, w, mask, bias, out);
    }
}

// Round 11
// 153.918 us; speedup vs baseline: 1.0132x; 1.0132x over previous
//
#include <hip/hip_runtime.h>
#include <hip/hip_bf16.h>
#include <stdint.h>

// out[b,n,o] = sum_t x[b,n,t] * (sum_g y[b,g]*w[g,o,t]*mask[o,t]) + bias[o]
// B=32 N=256 T=1024 O=1024 G=8.  bf16 MFMA path (absmax 0.031 vs thr 0.154).
//
//  R19 = R9 exact (best 149.5us) + NONTEMPORAL epilogue stores in gemm.
//       Mechanism: out=33.5MB = 4.2MB/XCD dirty through write-allocate L2 =
//       evicts the B(2MB)+A(1MB) working set the XCD=b swizzle parked there.
//       out has no downstream consumer in-pipeline -> L2 bypass is free
//       (unlike R8's prep-nt mistake: Wb/xb DID have a consumer).
//  Ledger: gemm invariant ~27us across syncthreads/counted-vmcnt (R9) and
//       2/3 blocks/CU (R10 regressed, reverted).  prep: 6 theories falsified,
//       fabric wall ~2.8 TB/s.  Fills ~81us uncontrollable.

#define B_ 32
#define N_ 256
#define T_ 1024
#define O_ 1024
#define G_ 8

#define WSTRIDE ((size_t)(O_ * T_ + 2048))   // padded b-slice stride, elems

#define BM 128
#define BN 128
#define BK 64            // elems; LDS row = 128 B = 8 x 16 B chunks
#define BUFSZ (BM * BK)  // 8192 elems = 16 KiB
#define NT (T_ / BK)     // 16 k-tiles

typedef __attribute__((__ext_vector_type__(8)))  __bf16 bf16x8;
typedef __attribute__((__ext_vector_type__(16))) float  f32x16;

__device__ __forceinline__ unsigned short f2bf(float f) {
    union { float f; uint32_t u; } v; v.f = f;
    uint32_t u = v.u;
    uint32_t r = (u + 0x7fffu + ((u >> 16) & 1u)) >> 16;  // RNE
    return (unsigned short)r;
}

__device__ __forceinline__ uint4 pack8(const float* a) {
    uint4 r;
    r.x = (uint32_t)f2bf(a[0]) | ((uint32_t)f2bf(a[1]) << 16);
    r.y = (uint32_t)f2bf(a[2]) | ((uint32_t)f2bf(a[3]) << 16);
    r.z = (uint32_t)f2bf(a[4]) | ((uint32_t)f2bf(a[5]) << 16);
    r.w = (uint32_t)f2bf(a[6]) | ((uint32_t)f2bf(a[7]) << 16);
    return r;
}

#define MIXB 1024   // O*T/4 threads / 256
#define CVTB 1024   // 262144 threads, 8 float4 each

// --- K1: fused prologue (R5 exact).
__global__ __launch_bounds__(256) void prep_kernel(
    const float* __restrict__ w,     // [G,O,T]
    const float* __restrict__ mask,  // [O,T]
    const float* __restrict__ y,     // [B,G]
    const float* __restrict__ x,     // [B,N,T]
    unsigned short* __restrict__ Wb, // [B][WSTRIDE] bf16 (padded)
    unsigned short* __restrict__ xb) // [B,N,T] bf16
{
    const int tid = threadIdx.x;
    if (blockIdx.x < MIXB) {
        __shared__ float ys[B_ * G_];          // 1 KiB
        ys[tid] = y[tid];
        __syncthreads();

        const int idx = blockIdx.x * 256 + tid;   // over O*T/4
        const int o   = idx >> 8;
        const int t   = (idx & 255) << 2;

        const float4 m4 = *(const float4*)(mask + (size_t)o * T_ + t);

        float wv[G_][4];
#pragma unroll
        for (int g = 0; g < G_; ++g) {
            const float4 a = *(const float4*)(w + ((size_t)g * O_ + o) * T_ + t);
            wv[g][0] = a.x * m4.x; wv[g][1] = a.y * m4.y;
            wv[g][2] = a.z * m4.z; wv[g][3] = a.w * m4.w;
        }
        unsigned short* dst = Wb + (size_t)o * T_ + t;
        const int bph = blockIdx.x & (B_ - 1);
#pragma unroll 4
        for (int bi = 0; bi < B_; ++bi) {
            const int b = (bi + bph) & (B_ - 1);
            const float4 y0 = *(const float4*)(ys + b * G_);      // LDS broadcast
            const float4 y1 = *(const float4*)(ys + b * G_ + 4);
            const float yv[G_] = {y0.x, y0.y, y0.z, y0.w, y1.x, y1.y, y1.z, y1.w};
            float acc[4] = {};
#pragma unroll
            for (int g = 0; g < G_; ++g)
#pragma unroll
                for (int j = 0; j < 4; ++j)
                    acc[j] += yv[g] * wv[g][j];
            ushort4 pk;
            pk.x = f2bf(acc[0]); pk.y = f2bf(acc[1]);
            pk.z = f2bf(acc[2]); pk.w = f2bf(acc[3]);
            *(ushort4*)(dst + (size_t)b * WSTRIDE) = pk;
        }
    } else {
        const int i = (blockIdx.x - MIXB) * 256 + tid;
        const float4* x4 = (const float4*)x;
        uint4* o4 = (uint4*)xb;
#pragma unroll
        for (int j = 0; j < 4; ++j) {
            const size_t f4 = (size_t)j * 524288 + (size_t)i * 2;
            const float4 a = x4[f4];
            const float4 b = x4[f4 + 1];
            const float v[8] = {a.x, a.y, a.z, a.w, b.x, b.y, b.z, b.w};
            o4[(size_t)j * 262144 + i] = pack8(v);
        }
    }
}

__device__ __forceinline__ void load16_to_lds(const unsigned short* g, unsigned short* l) {
    __builtin_amdgcn_global_load_lds(
        (const __attribute__((address_space(1))) unsigned char*)g,
        (__attribute__((address_space(3))) unsigned char*)l,
        16, 0, 0);
}

#define VMCNT_8 asm volatile("s_waitcnt vmcnt(8)" ::: "memory")
#define VMCNT_0 asm volatile("s_waitcnt vmcnt(0)" ::: "memory")
#define BARRIER asm volatile("s_barrier" ::: "memory")

// --- K2: batched GEMM, C = A . B^T, K-major bf16, mfma_32x32x16.
// 256 threads = 4 waves (2m x 2n), wave tile 64x64 = 2x2 of 32x32, acc 2x2xf32x16.
// A-frag: m=lane&31, k=(lane>>5)*8+j; B-frag symmetric.
// C/D: col=lane&31, row=(reg&3)+8*(reg>>2)+4*(lane>>5) [m74/m101].
// LDS chunk c of row r holds global chunk (c ^ (r&7)) -> conflict-free b128.
// Grid = (b, tm, tn): XCD = linear%8 = b%8 -> same-b blocks colocate on an XCD.
// K-loop: counted-vmcnt dbuf (8 loads/tile ride across raw s_barriers).
// Epilogue: nontemporal stores (out = 4.2MB/XCD dirty would evict A/B from L2).
__global__ __launch_bounds__(256, 2) void gemm_kernel(
    const unsigned short* __restrict__ xb,   // [B][N_][T_] bf16
    const unsigned short* __restrict__ Wb,   // [B][WSTRIDE] bf16 (padded)
    const float* __restrict__ bias,          // [O_]
    float* __restrict__ out)                 // [B][N_][O_] f32
{
    __shared__ __align__(16) unsigned short lA[2 * BUFSZ];  // 32 KiB
    __shared__ __align__(16) unsigned short lB[2 * BUFSZ];  // 32 KiB

    const int b  = blockIdx.x;   // 0..31  (XCD = b%8)
    const int tm = blockIdx.y;   // 0..1   (n tiles)
    const int tn = blockIdx.z;   // 0..7   (o tiles)

    const int tid  = threadIdx.x;
    const int lane = tid & 63;
    const int wave = tid >> 6;          // 0..3
    const int wm   = (wave >> 1) * 64;
    const int wn   = (wave & 1) * 64;

    const unsigned short* Ab = xb + (size_t)b * N_ * T_ + (size_t)(tm * BM) * T_;
    const unsigned short* Bb = Wb + (size_t)b * WSTRIDE + (size_t)(tn * BN) * T_;

    // staging (256 thr): round i: LDS elem tid*8 + i*2048 -> row tid/8 + i*32
    const int srow   = tid >> 3;                 // 0..31
    const int schunk = (tid & 7) ^ (srow & 7);   // (i*32)&7==0 -> round-invariant
    const unsigned short* ga0 = Ab + (size_t)srow * T_ + schunk * 8;
    const unsigned short* gb0 = Bb + (size_t)srow * T_ + schunk * 8;

#define STAGE(buf, kt)                                                          \
    {                                                                           \
        unsigned short* lad = lA + (buf) * BUFSZ + tid * 8;                     \
        unsigned short* lbd = lB + (buf) * BUFSZ + tid * 8;                     \
        _Pragma("unroll")                                                       \
        for (int i_ = 0; i_ < 4; ++i_) {                                        \
            load16_to_lds(ga0 + (kt) + (size_t)(i_ * 32) * T_, lad + i_ * 2048);\
            load16_to_lds(gb0 + (kt) + (size_t)(i_ * 32) * T_, lbd + i_ * 2048);\
        }                                                                       \
    }

    f32x16 acc[2][2] = {};

    const int fr   = lane & 31;      // fragment row within 32
    const int half = lane >> 5;      // k-half 0/1 (8 elems each)
    const int sw   = fr & 7;         // swizzle term (wm, mi*32 are multiples of 8)

#define COMPUTE(buf)                                                            \
    {                                                                           \
        const unsigned short* la = lA + (buf) * BUFSZ;                          \
        const unsigned short* lb = lB + (buf) * BUFSZ;                          \
        _Pragma("unroll")                                                       \
        for (int ks = 0; ks < 4; ++ks) {                                        \
            const int cp = (((ks * 2 + half)) ^ sw) * 8;                        \
            bf16x8 afr[2], bfr[2];                                              \
            _Pragma("unroll")                                                   \
            for (int i_ = 0; i_ < 2; ++i_)                                      \
                afr[i_] = *(const bf16x8*)(la + (wm + i_ * 32 + fr) * BK + cp); \
            _Pragma("unroll")                                                   \
            for (int i_ = 0; i_ < 2; ++i_)                                      \
                bfr[i_] = *(const bf16x8*)(lb + (wn + i_ * 32 + fr) * BK + cp); \
            _Pragma("unroll")                                                   \
            for (int mi = 0; mi < 2; ++mi)                                      \
                _Pragma("unroll")                                               \
                for (int ni = 0; ni < 2; ++ni)                                  \
                    acc[mi][ni] = __builtin_amdgcn_mfma_f32_32x32x16_bf16(      \
                        afr[mi], bfr[ni], acc[mi][ni], 0, 0, 0);                \
        }                                                                       \
    }

    STAGE(0, 0)
    STAGE(1, BK)
    // steady state: entering iter t, tiles t (8 loads) + t+1 (8 loads) issued.
    // vmcnt(8) completes tile t (oldest 8); t+1's 8 ride across the barriers.
    for (int t = 0; t < NT - 1; ++t) {
        const int c = t & 1;
        VMCNT_8;
        BARRIER;                       // buf c complete on all waves
        COMPUTE(c)
        BARRIER;                       // all waves done reading buf c
        if (t < NT - 2) STAGE(c, (t + 2) * BK)
    }
    VMCNT_0;
    BARRIER;                           // last tile staged everywhere
    COMPUTE(1)

    // Epilogue: D col=lane&31, row=(reg&3)+8*(reg>>2)+4*(lane>>5)  + bias.
    // Nontemporal: out is not re-read in-pipeline; keep L2 for A/B tiles.
    float* outb = out + (size_t)b * N_ * O_ + (size_t)(tm * BM) * O_ + (tn * BN);
    const int cn = lane & 31;
    const int rb = (lane >> 5) * 4;
#pragma unroll
    for (int ni = 0; ni < 2; ++ni) {
        const int col = wn + ni * 32 + cn;
        const float bv = bias[tn * BN + col];
#pragma unroll
        for (int mi = 0; mi < 2; ++mi) {
#pragma unroll
            for (int r = 0; r < 16; ++r) {
                const int row = wm + mi * 32 + rb + (r & 3) + 8 * (r >> 2);
                __builtin_nontemporal_store(acc[mi][ni][r] + bv,
                                            &outb[(size_t)row * O_ + col]);
            }
        }
    }
}

// --- Fallback (ws too small): correct fp32 path.
__global__ __launch_bounds__(256) void naive_kernel(
    const float* __restrict__ x, const float* __restrict__ y,
    const float* __restrict__ w, const float* __restrict__ mask,
    const float* __restrict__ bias, float* __restrict__ out)
{
    const int oc = blockIdx.x & 3;
    const int n  = (blockIdx.x >> 2) & (N_ - 1);
    const int b  = blockIdx.x >> 10;

    __shared__ float xs[T_];
    __shared__ float ys[G_];
    const float* xrow = x + ((size_t)b * N_ + n) * T_;
    for (int i = threadIdx.x; i < T_ / 4; i += 256)
        ((float4*)xs)[i] = ((const float4*)xrow)[i];
    if (threadIdx.x < G_) ys[threadIdx.x] = y[b * G_ + threadIdx.x];
    __syncthreads();

    const int o = oc * 256 + threadIdx.x;
    float acc = 0.f;
    for (int t = 0; t < T_; t += 4) {
        const float4 m4 = *(const float4*)(mask + (size_t)o * T_ + t);
        float4 s = {0.f, 0.f, 0.f, 0.f};
#pragma unroll
        for (int g = 0; g < G_; ++g) {
            const float4 w4 = *(const float4*)(w + ((size_t)g * O_ + o) * T_ + t);
            const float yv = ys[g];
            s.x += yv * w4.x; s.y += yv * w4.y; s.z += yv * w4.z; s.w += yv * w4.w;
        }
        acc += xs[t] * m4.x * s.x + xs[t + 1] * m4.y * s.y
             + xs[t + 2] * m4.z * s.z + xs[t + 3] * m4.w * s.w;
    }
    out[((size_t)b * N_ + n) * O_ + o] = acc + bias[o];
}

extern "C" void kernel_launch(void* const* d_in, const int* in_sizes, int n_in,
                              void* d_out, int out_size, void* d_ws, size_t ws_size,
                              hipStream_t stream) {
    const float* x    = (const float*)d_in[0];
    const float* y    = (const float*)d_in[1];
    const float* w    = (const float*)d_in[2];
    const float* mask = (const float*)d_in[3];
    const float* bias = (const float*)d_in[4];
    float* out = (float*)d_out;

    const size_t wb_bytes = (size_t)B_ * WSTRIDE * sizeof(unsigned short); // 64 MiB + 128 KB
    const size_t xb_bytes = (size_t)B_ * N_ * T_ * sizeof(unsigned short); // 16 MiB

    if (ws_size >= wb_bytes + xb_bytes) {
        unsigned short* Wb = (unsigned short*)d_ws;
        unsigned short* xb = (unsigned short*)((char*)d_ws + wb_bytes);
        prep_kernel<<<MIXB + CVTB, 256, 0, stream>>>(w, mask, y, x, Wb, xb);
        dim3 grid(B_, N_ / BM, O_ / BN);   // x=b -> XCD=b%8: A,B L2-resident
        gemm_kernel<<<grid, 256, 0, stream>>>(xb, Wb, bias, out);
    } else {
        naive_kernel<<<B_ * N_ * (O_ / 256), 256, 0, stream>>>(x, y, w, mask, bias, out);
    }
}

// Round 12
// 150.048 us; speedup vs baseline: 1.0393x; 1.0258x over previous
//
#include <hip/hip_runtime.h>
#include <hip/hip_bf16.h>
#include <stdint.h>

// out[b,n,o] = sum_t x[b,n,t] * (sum_g y[b,g]*w[g,o,t]*mask[o,t]) + bias[o]
// B=32 N=256 T=1024 O=1024 G=8.  bf16 MFMA path (absmax 0.031 vs thr 0.154).
//
//  R20 = R9 EXACT (session best: 149.5us).  Final configuration.
//  Ledger (what's known, so nobody re-treads):
//   prep 41.6us: 7 theories falsified (store width 8/16B, [B][O][T] scatter vs
//     [O][B][T] window vs dense slab, occupancy 13->50%, VMEM 105->41/thr,
//     load pipelining, mix/cvt split [-9us: keep fused], nt stores [cool L3]).
//     Wall: ~2.8 TB/s fabric rate for 32-stream broadcast-write, traffic-ideal.
//   gemm ~27us: invariant across syncthreads vs counted-vmcnt, 2 vs 3
//     blocks/CU, 128x128 vs 64x128 tile, nt epilogue (-5us regress).  Wins:
//     XCD=b grid swizzle (R5).  L3-served; latency plateau.
//   cvt-into-gemm fusion: killed by arithmetic (R7 shows cvt rides ~free in
//     fused prep; moving it to gemm nets ~0).
//   fills ~81us: harness workspace re-poison, not controllable from source.

#define B_ 32
#define N_ 256
#define T_ 1024
#define O_ 1024
#define G_ 8

#define WSTRIDE ((size_t)(O_ * T_ + 2048))   // padded b-slice stride, elems

#define BM 128
#define BN 128
#define BK 64            // elems; LDS row = 128 B = 8 x 16 B chunks
#define BUFSZ (BM * BK)  // 8192 elems = 16 KiB
#define NT (T_ / BK)     // 16 k-tiles

typedef __attribute__((__ext_vector_type__(8)))  __bf16 bf16x8;
typedef __attribute__((__ext_vector_type__(16))) float  f32x16;

__device__ __forceinline__ unsigned short f2bf(float f) {
    union { float f; uint32_t u; } v; v.f = f;
    uint32_t u = v.u;
    uint32_t r = (u + 0x7fffu + ((u >> 16) & 1u)) >> 16;  // RNE
    return (unsigned short)r;
}

__device__ __forceinline__ uint4 pack8(const float* a) {
    uint4 r;
    r.x = (uint32_t)f2bf(a[0]) | ((uint32_t)f2bf(a[1]) << 16);
    r.y = (uint32_t)f2bf(a[2]) | ((uint32_t)f2bf(a[3]) << 16);
    r.z = (uint32_t)f2bf(a[4]) | ((uint32_t)f2bf(a[5]) << 16);
    r.w = (uint32_t)f2bf(a[6]) | ((uint32_t)f2bf(a[7]) << 16);
    return r;
}

#define MIXB 1024   // O*T/4 threads / 256
#define CVTB 1024   // 262144 threads, 8 float4 each

// --- K1: fused prologue (R5 exact).
__global__ __launch_bounds__(256) void prep_kernel(
    const float* __restrict__ w,     // [G,O,T]
    const float* __restrict__ mask,  // [O,T]
    const float* __restrict__ y,     // [B,G]
    const float* __restrict__ x,     // [B,N,T]
    unsigned short* __restrict__ Wb, // [B][WSTRIDE] bf16 (padded)
    unsigned short* __restrict__ xb) // [B,N,T] bf16
{
    const int tid = threadIdx.x;
    if (blockIdx.x < MIXB) {
        __shared__ float ys[B_ * G_];          // 1 KiB
        ys[tid] = y[tid];
        __syncthreads();

        const int idx = blockIdx.x * 256 + tid;   // over O*T/4
        const int o   = idx >> 8;
        const int t   = (idx & 255) << 2;

        const float4 m4 = *(const float4*)(mask + (size_t)o * T_ + t);

        float wv[G_][4];
#pragma unroll
        for (int g = 0; g < G_; ++g) {
            const float4 a = *(const float4*)(w + ((size_t)g * O_ + o) * T_ + t);
            wv[g][0] = a.x * m4.x; wv[g][1] = a.y * m4.y;
            wv[g][2] = a.z * m4.z; wv[g][3] = a.w * m4.w;
        }
        unsigned short* dst = Wb + (size_t)o * T_ + t;
        const int bph = blockIdx.x & (B_ - 1);
#pragma unroll 4
        for (int bi = 0; bi < B_; ++bi) {
            const int b = (bi + bph) & (B_ - 1);
            const float4 y0 = *(const float4*)(ys + b * G_);      // LDS broadcast
            const float4 y1 = *(const float4*)(ys + b * G_ + 4);
            const float yv[G_] = {y0.x, y0.y, y0.z, y0.w, y1.x, y1.y, y1.z, y1.w};
            float acc[4] = {};
#pragma unroll
            for (int g = 0; g < G_; ++g)
#pragma unroll
                for (int j = 0; j < 4; ++j)
                    acc[j] += yv[g] * wv[g][j];
            ushort4 pk;
            pk.x = f2bf(acc[0]); pk.y = f2bf(acc[1]);
            pk.z = f2bf(acc[2]); pk.w = f2bf(acc[3]);
            *(ushort4*)(dst + (size_t)b * WSTRIDE) = pk;
        }
    } else {
        const int i = (blockIdx.x - MIXB) * 256 + tid;
        const float4* x4 = (const float4*)x;
        uint4* o4 = (uint4*)xb;
#pragma unroll
        for (int j = 0; j < 4; ++j) {
            const size_t f4 = (size_t)j * 524288 + (size_t)i * 2;
            const float4 a = x4[f4];
            const float4 b = x4[f4 + 1];
            const float v[8] = {a.x, a.y, a.z, a.w, b.x, b.y, b.z, b.w};
            o4[(size_t)j * 262144 + i] = pack8(v);
        }
    }
}

__device__ __forceinline__ void load16_to_lds(const unsigned short* g, unsigned short* l) {
    __builtin_amdgcn_global_load_lds(
        (const __attribute__((address_space(1))) unsigned char*)g,
        (__attribute__((address_space(3))) unsigned char*)l,
        16, 0, 0);
}

#define VMCNT_8 asm volatile("s_waitcnt vmcnt(8)" ::: "memory")
#define VMCNT_0 asm volatile("s_waitcnt vmcnt(0)" ::: "memory")
#define BARRIER asm volatile("s_barrier" ::: "memory")

// --- K2: batched GEMM, C = A . B^T, K-major bf16, mfma_32x32x16.
// 256 threads = 4 waves (2m x 2n), wave tile 64x64 = 2x2 of 32x32, acc 2x2xf32x16.
// A-frag: m=lane&31, k=(lane>>5)*8+j; B-frag symmetric.
// C/D: col=lane&31, row=(reg&3)+8*(reg>>2)+4*(lane>>5) [m74/m101].
// LDS chunk c of row r holds global chunk (c ^ (r&7)) -> conflict-free b128.
// Grid = (b, tm, tn): XCD = linear%8 = b%8 -> same-b blocks colocate on an XCD.
// K-loop: counted-vmcnt dbuf (8 loads/tile ride across raw s_barriers).
__global__ __launch_bounds__(256, 2) void gemm_kernel(
    const unsigned short* __restrict__ xb,   // [B][N_][T_] bf16
    const unsigned short* __restrict__ Wb,   // [B][WSTRIDE] bf16 (padded)
    const float* __restrict__ bias,          // [O_]
    float* __restrict__ out)                 // [B][N_][O_] f32
{
    __shared__ __align__(16) unsigned short lA[2 * BUFSZ];  // 32 KiB
    __shared__ __align__(16) unsigned short lB[2 * BUFSZ];  // 32 KiB

    const int b  = blockIdx.x;   // 0..31  (XCD = b%8)
    const int tm = blockIdx.y;   // 0..1   (n tiles)
    const int tn = blockIdx.z;   // 0..7   (o tiles)

    const int tid  = threadIdx.x;
    const int lane = tid & 63;
    const int wave = tid >> 6;          // 0..3
    const int wm   = (wave >> 1) * 64;
    const int wn   = (wave & 1) * 64;

    const unsigned short* Ab = xb + (size_t)b * N_ * T_ + (size_t)(tm * BM) * T_;
    const unsigned short* Bb = Wb + (size_t)b * WSTRIDE + (size_t)(tn * BN) * T_;

    // staging (256 thr): round i: LDS elem tid*8 + i*2048 -> row tid/8 + i*32
    const int srow   = tid >> 3;                 // 0..31
    const int schunk = (tid & 7) ^ (srow & 7);   // (i*32)&7==0 -> round-invariant
    const unsigned short* ga0 = Ab + (size_t)srow * T_ + schunk * 8;
    const unsigned short* gb0 = Bb + (size_t)srow * T_ + schunk * 8;

#define STAGE(buf, kt)                                                          \
    {                                                                           \
        unsigned short* lad = lA + (buf) * BUFSZ + tid * 8;                     \
        unsigned short* lbd = lB + (buf) * BUFSZ + tid * 8;                     \
        _Pragma("unroll")                                                       \
        for (int i_ = 0; i_ < 4; ++i_) {                                        \
            load16_to_lds(ga0 + (kt) + (size_t)(i_ * 32) * T_, lad + i_ * 2048);\
            load16_to_lds(gb0 + (kt) + (size_t)(i_ * 32) * T_, lbd + i_ * 2048);\
        }                                                                       \
    }

    f32x16 acc[2][2] = {};

    const int fr   = lane & 31;      // fragment row within 32
    const int half = lane >> 5;      // k-half 0/1 (8 elems each)
    const int sw   = fr & 7;         // swizzle term (wm, mi*32 are multiples of 8)

#define COMPUTE(buf)                                                            \
    {                                                                           \
        const unsigned short* la = lA + (buf) * BUFSZ;                          \
        const unsigned short* lb = lB + (buf) * BUFSZ;                          \
        _Pragma("unroll")                                                       \
        for (int ks = 0; ks < 4; ++ks) {                                        \
            const int cp = (((ks * 2 + half)) ^ sw) * 8;                        \
            bf16x8 afr[2], bfr[2];                                              \
            _Pragma("unroll")                                                   \
            for (int i_ = 0; i_ < 2; ++i_)                                      \
                afr[i_] = *(const bf16x8*)(la + (wm + i_ * 32 + fr) * BK + cp); \
            _Pragma("unroll")                                                   \
            for (int i_ = 0; i_ < 2; ++i_)                                      \
                bfr[i_] = *(const bf16x8*)(lb + (wn + i_ * 32 + fr) * BK + cp); \
            _Pragma("unroll")                                                   \
            for (int mi = 0; mi < 2; ++mi)                                      \
                _Pragma("unroll")                                               \
                for (int ni = 0; ni < 2; ++ni)                                  \
                    acc[mi][ni] = __builtin_amdgcn_mfma_f32_32x32x16_bf16(      \
                        afr[mi], bfr[ni], acc[mi][ni], 0, 0, 0);                \
        }                                                                       \
    }

    STAGE(0, 0)
    STAGE(1, BK)
    // steady state: entering iter t, tiles t (8 loads) + t+1 (8 loads) issued.
    // vmcnt(8) completes tile t (oldest 8); t+1's 8 ride across the barriers.
    for (int t = 0; t < NT - 1; ++t) {
        const int c = t & 1;
        VMCNT_8;
        BARRIER;                       // buf c complete on all waves
        COMPUTE(c)
        BARRIER;                       // all waves done reading buf c
        if (t < NT - 2) STAGE(c, (t + 2) * BK)
    }
    VMCNT_0;
    BARRIER;                           // last tile staged everywhere
    COMPUTE(1)

    // Epilogue: D col=lane&31, row=(reg&3)+8*(reg>>2)+4*(lane>>5)  + bias.
    float* outb = out + (size_t)b * N_ * O_ + (size_t)(tm * BM) * O_ + (tn * BN);
    const int cn = lane & 31;
    const int rb = (lane >> 5) * 4;
#pragma unroll
    for (int ni = 0; ni < 2; ++ni) {
        const int col = wn + ni * 32 + cn;
        const float bv = bias[tn * BN + col];
#pragma unroll
        for (int mi = 0; mi < 2; ++mi) {
#pragma unroll
            for (int r = 0; r < 16; ++r) {
                const int row = wm + mi * 32 + rb + (r & 3) + 8 * (r >> 2);
                outb[(size_t)row * O_ + col] = acc[mi][ni][r] + bv;
            }
        }
    }
}

// --- Fallback (ws too small): correct fp32 path.
__global__ __launch_bounds__(256) void naive_kernel(
    const float* __restrict__ x, const float* __restrict__ y,
    const float* __restrict__ w, const float* __restrict__ mask,
    const float* __restrict__ bias, float* __restrict__ out)
{
    const int oc = blockIdx.x & 3;
    const int n  = (blockIdx.x >> 2) & (N_ - 1);
    const int b  = blockIdx.x >> 10;

    __shared__ float xs[T_];
    __shared__ float ys[G_];
    const float* xrow = x + ((size_t)b * N_ + n) * T_;
    for (int i = threadIdx.x; i < T_ / 4; i += 256)
        ((float4*)xs)[i] = ((const float4*)xrow)[i];
    if (threadIdx.x < G_) ys[threadIdx.x] = y[b * G_ + threadIdx.x];
    __syncthreads();

    const int o = oc * 256 + threadIdx.x;
    float acc = 0.f;
    for (int t = 0; t < T_; t += 4) {
        const float4 m4 = *(const float4*)(mask + (size_t)o * T_ + t);
        float4 s = {0.f, 0.f, 0.f, 0.f};
#pragma unroll
        for (int g = 0; g < G_; ++g) {
            const float4 w4 = *(const float4*)(w + ((size_t)g * O_ + o) * T_ + t);
            const float yv = ys[g];
            s.x += yv * w4.x; s.y += yv * w4.y; s.z += yv * w4.z; s.w += yv * w4.w;
        }
        acc += xs[t] * m4.x * s.x + xs[t + 1] * m4.y * s.y
             + xs[t + 2] * m4.z * s.z + xs[t + 3] * m4.w * s.w;
    }
    out[((size_t)b * N_ + n) * O_ + o] = acc + bias[o];
}

extern "C" void kernel_launch(void* const* d_in, const int* in_sizes, int n_in,
                              void* d_out, int out_size, void* d_ws, size_t ws_size,
                              hipStream_t stream) {
    const float* x    = (const float*)d_in[0];
    const float* y    = (const float*)d_in[1];
    const float* w    = (const float*)d_in[2];
    const float* mask = (const float*)d_in[3];
    const float* bias = (const float*)d_in[4];
    float* out = (float*)d_out;

    const size_t wb_bytes = (size_t)B_ * WSTRIDE * sizeof(unsigned short); // 64 MiB + 128 KB
    const size_t xb_bytes = (size_t)B_ * N_ * T_ * sizeof(unsigned short); // 16 MiB

    if (ws_size >= wb_bytes + xb_bytes) {
        unsigned short* Wb = (unsigned short*)d_ws;
        unsigned short* xb = (unsigned short*)((char*)d_ws + wb_bytes);
        prep_kernel<<<MIXB + CVTB, 256, 0, stream>>>(w, mask, y, x, Wb, xb);
        dim3 grid(B_, N_ / BM, O_ / BN);   // x=b -> XCD=b%8: A,B L2-resident
        gemm_kernel<<<grid, 256, 0, stream>>>(xb, Wb, bias, out);
    } else {
        naive_kernel<<<B_ * N_ * (O_ / 256), 256, 0, stream>>>(x, y, w, mask, bias, out);
    }
}